// Round 1
// baseline (1649.680 us; speedup 1.0000x reference)
//
#include <hip/hip_runtime.h>
#include <hip/hip_bf16.h>
#include <type_traits>
#include <math.h>

// ---------------- helpers ----------------
__device__ __forceinline__ float bf2f(unsigned int u16) {
    union { unsigned int i; float f; } x; x.i = (u16 & 0xffffu) << 16; return x.f;
}
__device__ __forceinline__ unsigned int f2bf(float f) {
    union { float f; unsigned int i; } x; x.f = f;
    unsigned int i = x.i;
    unsigned int r = i + 0x7fffu + ((i >> 16) & 1u);
    return r >> 16; // RNE
}

#define SLOPE 0.2f

// ---------------- CSR build ----------------
__global__ void k_hist(const int* __restrict__ tgt, int* __restrict__ cnt, int E) {
    int i = blockIdx.x * blockDim.x + threadIdx.x;
    if (i < E) atomicAdd(&cnt[tgt[i]], 1);
}

__global__ void __launch_bounds__(1024) k_scan1(const int* __restrict__ in, int* __restrict__ out,
                                                int* __restrict__ bsums, int n) {
    __shared__ int sm[1024];
    int i = blockIdx.x * 1024 + threadIdx.x;
    int v = (i < n) ? in[i] : 0;
    sm[threadIdx.x] = v; __syncthreads();
    for (int ofs = 1; ofs < 1024; ofs <<= 1) {
        int t = (threadIdx.x >= ofs) ? sm[threadIdx.x - ofs] : 0;
        __syncthreads();
        sm[threadIdx.x] += t;
        __syncthreads();
    }
    if (i < n) out[i] = sm[threadIdx.x];
    if (threadIdx.x == 1023) bsums[blockIdx.x] = sm[1023];
}

__global__ void __launch_bounds__(1024) k_scan2(int* bsums, int nb) {
    __shared__ int sm[1024];
    int v = (threadIdx.x < nb) ? bsums[threadIdx.x] : 0;
    sm[threadIdx.x] = v; __syncthreads();
    for (int ofs = 1; ofs < 1024; ofs <<= 1) {
        int t = (threadIdx.x >= ofs) ? sm[threadIdx.x - ofs] : 0;
        __syncthreads();
        sm[threadIdx.x] += t;
        __syncthreads();
    }
    if (threadIdx.x < nb) bsums[threadIdx.x] = sm[threadIdx.x] - v; // exclusive
}

__global__ void __launch_bounds__(1024) k_scan3(int* __restrict__ out1, const int* __restrict__ bsums,
                                                int* __restrict__ off0, int n) {
    int i = blockIdx.x * 1024 + threadIdx.x;
    if (i < n) out1[i] += bsums[blockIdx.x];
    if (i == 0) off0[0] = 0;
}

__global__ void k_scatter(const int* __restrict__ ei, const float* __restrict__ ew,
                          const int* __restrict__ off, int* __restrict__ fill,
                          int* __restrict__ ssrc, float* __restrict__ sew, int E) {
    int e = blockIdx.x * blockDim.x + threadIdx.x;
    if (e < E) {
        int s = ei[e], t = ei[E + e];
        int pos = off[t] + atomicAdd(&fill[t], 1);
        ssrc[pos] = s; sew[pos] = ew[e];
    }
}

__global__ void k_combo(const int* __restrict__ ri, const int* __restrict__ ci,
                        int* __restrict__ combo, int V) {
    int v = blockIdx.x * blockDim.x + threadIdx.x;
    if (v < V) combo[v] = ri[v] * 64 + ci[v];
}

// ---------------- PE projection tables ----------------
// blocks 0..255: A[pos] = row_pe[pos] @ W_in[768:960]; blocks 256..319: B[pos]=col_pe@W_in[960:1152]
__global__ void __launch_bounds__(256) k_peproj(const float* __restrict__ W_in, float* __restrict__ AB) {
    __shared__ float pe[192];
    int blk = blockIdx.x;
    bool isA = blk < 256;
    int pos = isA ? blk : blk - 256;
    const float* Wb = W_in + (size_t)(isA ? 768 : 960) * 256;
    int tid = threadIdx.x;
    if (tid < 192) {
        float div = expf(-(float)(tid & ~1) * (logf(10000.0f) / 192.0f));
        float ang = (float)pos * div;
        pe[tid] = (tid & 1) ? cosf(ang) : sinf(ang);
    }
    __syncthreads();
    float acc = 0.f;
    #pragma unroll 8
    for (int d = 0; d < 192; ++d) acc = fmaf(pe[d], Wb[d * 256 + tid], acc);
    AB[blk * 256 + tid] = acc;
}

// ---------------- h0 table: A[r]+B[c]+b_in -> LN -> ReLU (16384 combos) ----------------
__global__ void __launch_bounds__(256) k_h0(const float* __restrict__ AB, const float* __restrict__ b_in,
                                            const float* __restrict__ g, const float* __restrict__ b,
                                            float* __restrict__ h0t) {
    int wid = threadIdx.x >> 6, lane = threadIdx.x & 63;
    int m = blockIdx.x * 4 + wid; // 0..16383
    int r = m >> 6, c = m & 63;
    float4 a  = ((const float4*)(AB + (size_t)r * 256))[lane];
    float4 bb = ((const float4*)(AB + (size_t)(256 + c) * 256))[lane];
    float4 bi = ((const float4*)b_in)[lane];
    float x0 = a.x + bb.x + bi.x, x1 = a.y + bb.y + bi.y;
    float x2 = a.z + bb.z + bi.z, x3 = a.w + bb.w + bi.w;
    float s = x0 + x1 + x2 + x3;
    #pragma unroll
    for (int msk = 1; msk < 64; msk <<= 1) s += __shfl_xor(s, msk);
    float mu = s * (1.f / 256.f);
    float d0 = x0 - mu, d1 = x1 - mu, d2 = x2 - mu, d3 = x3 - mu;
    float sq = d0 * d0 + d1 * d1 + d2 * d2 + d3 * d3;
    #pragma unroll
    for (int msk = 1; msk < 64; msk <<= 1) sq += __shfl_xor(sq, msk);
    float rstd = rsqrtf(sq * (1.f / 256.f) + 1e-5f);
    float4 gv = ((const float4*)g)[lane], bv = ((const float4*)b)[lane];
    float4 y;
    y.x = fmaxf(fmaf(d0 * rstd, gv.x, bv.x), 0.f);
    y.y = fmaxf(fmaf(d1 * rstd, gv.y, bv.y), 0.f);
    y.z = fmaxf(fmaf(d2 * rstd, gv.z, bv.z), 0.f);
    y.w = fmaxf(fmaf(d3 * rstd, gv.w, bv.w), 0.f);
    ((float4*)(h0t + (size_t)m * 256))[lane] = y;
}

// ---------------- f32 tiled GEMM: C[M][256] = act(A[M][256] @ W[256][256] + bias) ----------------
// TA: float or unsigned short (bf16). TC: float or unsigned short (bf16).
template <typename TA, typename TC, bool LEAKY>
__global__ void __launch_bounds__(256) k_gemm(const TA* __restrict__ A, const float* __restrict__ W,
                                              const float* __restrict__ bias, TC* __restrict__ C, int M) {
    __shared__ float As[32][64];
    __shared__ float Ws[32][64];
    int tid = threadIdx.x;
    int tx = tid & 15, ty = tid >> 4;
    int R0 = blockIdx.x * 64, C0 = blockIdx.y * 64;
    float acc[4][4] = {};
    int ra = tid >> 2, ck = (tid & 3) * 8; // A: row ra, k-offsets ck..ck+7
    int kw = tid >> 3, cw = (tid & 7) * 8; // W: row kw, cols cw..cw+7
    for (int k0 = 0; k0 < 256; k0 += 32) {
        int arow = R0 + ra;
        if constexpr (std::is_same<TA, float>::value) {
            float4 a0 = {0.f, 0.f, 0.f, 0.f}, a1 = {0.f, 0.f, 0.f, 0.f};
            if (arow < M) {
                a0 = *(const float4*)(A + (size_t)arow * 256 + k0 + ck);
                a1 = *(const float4*)(A + (size_t)arow * 256 + k0 + ck + 4);
            }
            As[ck + 0][ra] = a0.x; As[ck + 1][ra] = a0.y; As[ck + 2][ra] = a0.z; As[ck + 3][ra] = a0.w;
            As[ck + 4][ra] = a1.x; As[ck + 5][ra] = a1.y; As[ck + 6][ra] = a1.z; As[ck + 7][ra] = a1.w;
        } else {
            uint4 u = {0u, 0u, 0u, 0u};
            if (arow < M) u = *(const uint4*)(A + (size_t)arow * 256 + k0 + ck);
            As[ck + 0][ra] = bf2f(u.x); As[ck + 1][ra] = bf2f(u.x >> 16);
            As[ck + 2][ra] = bf2f(u.y); As[ck + 3][ra] = bf2f(u.y >> 16);
            As[ck + 4][ra] = bf2f(u.z); As[ck + 5][ra] = bf2f(u.z >> 16);
            As[ck + 6][ra] = bf2f(u.w); As[ck + 7][ra] = bf2f(u.w >> 16);
        }
        float4 w0 = *(const float4*)(W + (size_t)(k0 + kw) * 256 + C0 + cw);
        float4 w1 = *(const float4*)(W + (size_t)(k0 + kw) * 256 + C0 + cw + 4);
        *(float4*)&Ws[kw][cw] = w0;
        *(float4*)&Ws[kw][cw + 4] = w1;
        __syncthreads();
        #pragma unroll
        for (int kk = 0; kk < 32; ++kk) {
            float4 av = *(const float4*)&As[kk][ty * 4];
            float4 bv = *(const float4*)&Ws[kk][tx * 4];
            float aa[4] = {av.x, av.y, av.z, av.w};
            float bb[4] = {bv.x, bv.y, bv.z, bv.w};
            #pragma unroll
            for (int r = 0; r < 4; ++r)
                #pragma unroll
                for (int c = 0; c < 4; ++c) acc[r][c] = fmaf(aa[r], bb[c], acc[r][c]);
        }
        __syncthreads();
    }
    int cbase = C0 + tx * 4;
    float bs[4] = {bias[cbase], bias[cbase + 1], bias[cbase + 2], bias[cbase + 3]};
    #pragma unroll
    for (int r = 0; r < 4; ++r) {
        int row = R0 + ty * 4 + r;
        if (row < M) {
            float v[4];
            #pragma unroll
            for (int c = 0; c < 4; ++c) {
                float t = acc[r][c] + bs[c];
                if (LEAKY) t = t > 0.f ? t : SLOPE * t;
                v[c] = t;
            }
            if constexpr (std::is_same<TC, float>::value) {
                float4 o = {v[0], v[1], v[2], v[3]};
                *(float4*)(C + (size_t)row * 256 + cbase) = o;
            } else {
                uint2 o;
                o.x = f2bf(v[0]) | (f2bf(v[1]) << 16);
                o.y = f2bf(v[2]) | (f2bf(v[3]) << 16);
                *(uint2*)(C + (size_t)row * 256 + cbase) = o;
            }
        }
    }
}

// ---------------- edge aggregation: one wave per target ----------------
// lane layout: head h = lane>>4, 4 features per lane -> Q/K/V row element offset = lane*4
template <bool USE_COMBO>
__global__ void __launch_bounds__(256) k_edge(const int* __restrict__ off, const int* __restrict__ ssrc,
                                              const float* __restrict__ sew, const int* __restrict__ combo,
                                              const unsigned short* __restrict__ Q,
                                              const unsigned short* __restrict__ K,
                                              const unsigned short* __restrict__ Vv,
                                              const float* __restrict__ We_l, const float* __restrict__ be_l,
                                              float* __restrict__ out, int V) {
    int wid = threadIdx.x >> 6, lane = threadIdx.x & 63;
    int t = blockIdx.x * 4 + wid;
    if (t >= V) return;
    int h = lane >> 4;
    int krow = USE_COMBO ? combo[t] : t;
    uint2 ku = *(const uint2*)(K + (size_t)krow * 256 + lane * 4);
    float k0 = bf2f(ku.x), k1 = bf2f(ku.x >> 16), k2 = bf2f(ku.y), k3 = bf2f(ku.y >> 16);
    float Weh = We_l[h], beh = be_l[h];
    float n0 = 0.f, n1 = 0.f, n2 = 0.f, n3 = 0.f, den = 0.f;
    int beg = off[t], end = off[t + 1];
    for (int e0 = beg; e0 < end; e0 += 64) {
        int nrem = end - e0; if (nrem > 64) nrem = 64;
        int sv = 0; float wv = 0.f;
        if (lane < nrem) {
            sv = ssrc[e0 + lane];
            wv = sew[e0 + lane];
            if (USE_COMBO) sv = combo[sv];
        }
        for (int i = 0; i < nrem; ++i) {
            int srow = __shfl(sv, i);
            float w = __shfl(wv, i);
            uint2 qu = *(const uint2*)(Q + (size_t)srow * 256 + lane * 4);
            float p = bf2f(qu.x) * k0 + bf2f(qu.x >> 16) * k1 + bf2f(qu.y) * k2 + bf2f(qu.y >> 16) * k3;
            p += __shfl_xor(p, 1);
            p += __shfl_xor(p, 2);
            p += __shfl_xor(p, 4);
            p += __shfl_xor(p, 8);
            float bias = fmaf(w, Weh, beh);
            bias = bias > 0.f ? bias : SLOPE * bias;
            float ex = expf(fmaf(p, 0.125f, bias));
            den += ex;
            float cc = ex * w;
            uint2 vu = *(const uint2*)(Vv + (size_t)srow * 256 + lane * 4);
            n0 = fmaf(cc, bf2f(vu.x), n0);
            n1 = fmaf(cc, bf2f(vu.x >> 16), n1);
            n2 = fmaf(cc, bf2f(vu.y), n2);
            n3 = fmaf(cc, bf2f(vu.y >> 16), n3);
        }
    }
    float inv = 1.f / (den + 1e-16f);
    float4 o = {n0 * inv, n1 * inv, n2 * inv, n3 * inv};
    *(float4*)(out + (size_t)t * 256 + lane * 4) = o;
}

// ---------------- launcher ----------------
extern "C" void kernel_launch(void* const* d_in, const int* in_sizes, int n_in,
                              void* d_out, int out_size, void* d_ws, size_t ws_size,
                              hipStream_t stream) {
    const int*   row_idx = (const int*)d_in[0];
    const int*   col_idx = (const int*)d_in[1];
    const int*   ei      = (const int*)d_in[2];
    const float* ew      = (const float*)d_in[3];
    const float* W_in    = (const float*)d_in[4];
    const float* b_in    = (const float*)d_in[5];
    const float* ln_g    = (const float*)d_in[6];
    const float* ln_b    = (const float*)d_in[7];
    const float* Wq      = (const float*)d_in[8];
    const float* bq      = (const float*)d_in[9];
    const float* Wk      = (const float*)d_in[10];
    const float* bk      = (const float*)d_in[11];
    const float* Wv      = (const float*)d_in[12];
    const float* bv      = (const float*)d_in[13];
    const float* Wo      = (const float*)d_in[14];
    const float* bo      = (const float*)d_in[15];
    const float* We      = (const float*)d_in[16];
    const float* be      = (const float*)d_in[17];

    const int V = in_sizes[0];
    const int E = in_sizes[3];
    const int NC = 16384; // 256*64 distinct (row,col) combos

    // workspace carve-up
    char* w = (char*)d_ws;
    size_t o = 0;
    auto alloc = [&](size_t bytes) -> char* {
        char* p = w + o;
        o = (o + bytes + 255) & ~(size_t)255;
        return p;
    };
    int*   cnt     = (int*)alloc((size_t)V * 4);
    int*   fill    = (int*)alloc((size_t)V * 4);
    int*   csr_off = (int*)alloc((size_t)(V + 1) * 4);
    int*   bsums   = (int*)alloc(1024 * 4);
    int*   csr_src = (int*)alloc((size_t)E * 4);
    float* csr_ew  = (float*)alloc((size_t)E * 4);
    int*   combo   = (int*)alloc((size_t)V * 4);
    float* AB      = (float*)alloc((size_t)320 * 256 * 4);
    float* h0t     = (float*)alloc((size_t)NC * 256 * 4);
    unsigned short* Qt = (unsigned short*)alloc((size_t)NC * 256 * 2);
    unsigned short* Kt = (unsigned short*)alloc((size_t)NC * 256 * 2);
    unsigned short* Vt = (unsigned short*)alloc((size_t)NC * 256 * 2);
    unsigned short* h1 = (unsigned short*)alloc((size_t)V * 256 * 2);
    unsigned short* Q2 = (unsigned short*)alloc((size_t)V * 256 * 2);
    unsigned short* K2 = (unsigned short*)alloc((size_t)V * 256 * 2);
    unsigned short* V2 = (unsigned short*)alloc((size_t)V * 256 * 2);
    float* out2 = (float*)alloc((size_t)V * 256 * 4);
    float* out1 = (float*)d_out; // layer-1 aggregation scratch lives in d_out

    hipMemsetAsync(cnt, 0, (size_t)V * 4, stream);
    hipMemsetAsync(fill, 0, (size_t)V * 4, stream);

    int eb = (E + 255) / 256;
    int nscan = (V + 1023) / 1024;
    k_hist<<<eb, 256, 0, stream>>>(ei + E, cnt, E);
    k_scan1<<<nscan, 1024, 0, stream>>>(cnt, csr_off + 1, bsums, V);
    k_scan2<<<1, 1024, 0, stream>>>(bsums, nscan);
    k_scan3<<<nscan, 1024, 0, stream>>>(csr_off + 1, bsums, csr_off, V);
    k_scatter<<<eb, 256, 0, stream>>>(ei, ew, csr_off, fill, csr_src, csr_ew, E);
    k_combo<<<(V + 255) / 256, 256, 0, stream>>>(row_idx, col_idx, combo, V);

    k_peproj<<<320, 256, 0, stream>>>(W_in, AB);
    k_h0<<<NC / 4, 256, 0, stream>>>(AB, b_in, ln_g, ln_b, h0t);

    dim3 g1(NC / 64, 4);
    k_gemm<float, unsigned short, false><<<g1, 256, 0, stream>>>(h0t, Wq, bq, Qt, NC);
    k_gemm<float, unsigned short, false><<<g1, 256, 0, stream>>>(h0t, Wk, bk, Kt, NC);
    k_gemm<float, unsigned short, false><<<g1, 256, 0, stream>>>(h0t, Wv, bv, Vt, NC);

    int tb = (V + 3) / 4;
    k_edge<true><<<tb, 256, 0, stream>>>(csr_off, csr_src, csr_ew, combo, Qt, Kt, Vt,
                                         We, be, out1, V);

    dim3 g2((V + 63) / 64, 4);
    k_gemm<float, unsigned short, true><<<g2, 256, 0, stream>>>(out1, Wo, bo, h1, V);
    k_gemm<unsigned short, unsigned short, false><<<g2, 256, 0, stream>>>(h1, Wq + 65536, bq + 256, Q2, V);
    k_gemm<unsigned short, unsigned short, false><<<g2, 256, 0, stream>>>(h1, Wk + 65536, bk + 256, K2, V);
    k_gemm<unsigned short, unsigned short, false><<<g2, 256, 0, stream>>>(h1, Wv + 65536, bv + 256, V2, V);

    k_edge<false><<<tb, 256, 0, stream>>>(csr_off, csr_src, csr_ew, combo, Q2, K2, V2,
                                          We + 4, be + 4, out2, V);

    k_gemm<float, float, true><<<g2, 256, 0, stream>>>(out2, Wo + 65536, bo + 256, (float*)d_out, V);
}

// Round 2
// 874.316 us; speedup vs baseline: 1.8868x; 1.8868x over previous
//
#include <hip/hip_runtime.h>
#include <hip/hip_bf16.h>
#include <type_traits>
#include <math.h>

typedef __attribute__((ext_vector_type(8))) short bf16x8;
typedef __attribute__((ext_vector_type(4))) float f32x4;

// ---------------- helpers ----------------
__device__ __forceinline__ float bf2f(unsigned int u16) {
    union { unsigned int i; float f; } x; x.i = (u16 & 0xffffu) << 16; return x.f;
}
__device__ __forceinline__ unsigned int f2bf(float f) {
    union { float f; unsigned int i; } x; x.f = f;
    unsigned int i = x.i;
    unsigned int r = i + 0x7fffu + ((i >> 16) & 1u);
    return r >> 16; // RNE
}

#define SLOPE 0.2f

// ---------------- CSR build ----------------
__global__ void k_hist(const int* __restrict__ tgt, int* __restrict__ cnt, int E) {
    int i = blockIdx.x * blockDim.x + threadIdx.x;
    if (i < E) atomicAdd(&cnt[tgt[i]], 1);
}

__global__ void __launch_bounds__(1024) k_scan1(const int* __restrict__ in, int* __restrict__ out,
                                                int* __restrict__ bsums, int n) {
    __shared__ int sm[1024];
    int i = blockIdx.x * 1024 + threadIdx.x;
    int v = (i < n) ? in[i] : 0;
    sm[threadIdx.x] = v; __syncthreads();
    for (int ofs = 1; ofs < 1024; ofs <<= 1) {
        int t = (threadIdx.x >= ofs) ? sm[threadIdx.x - ofs] : 0;
        __syncthreads();
        sm[threadIdx.x] += t;
        __syncthreads();
    }
    if (i < n) out[i] = sm[threadIdx.x];
    if (threadIdx.x == 1023) bsums[blockIdx.x] = sm[1023];
}

__global__ void __launch_bounds__(1024) k_scan2(int* bsums, int nb) {
    __shared__ int sm[1024];
    int v = (threadIdx.x < nb) ? bsums[threadIdx.x] : 0;
    sm[threadIdx.x] = v; __syncthreads();
    for (int ofs = 1; ofs < 1024; ofs <<= 1) {
        int t = (threadIdx.x >= ofs) ? sm[threadIdx.x - ofs] : 0;
        __syncthreads();
        sm[threadIdx.x] += t;
        __syncthreads();
    }
    if (threadIdx.x < nb) bsums[threadIdx.x] = sm[threadIdx.x] - v; // exclusive
}

__global__ void __launch_bounds__(1024) k_scan3(int* __restrict__ out1, const int* __restrict__ bsums,
                                                int* __restrict__ off0, int n) {
    int i = blockIdx.x * 1024 + threadIdx.x;
    if (i < n) out1[i] += bsums[blockIdx.x];
    if (i == 0) off0[0] = 0;
}

__global__ void k_scatter(const int* __restrict__ ei, const float* __restrict__ ew,
                          const int* __restrict__ off, int* __restrict__ fill,
                          int* __restrict__ ssrc, float* __restrict__ sew, int E) {
    int e = blockIdx.x * blockDim.x + threadIdx.x;
    if (e < E) {
        int s = ei[e], t = ei[E + e];
        int pos = off[t] + atomicAdd(&fill[t], 1);
        ssrc[pos] = s; sew[pos] = ew[e];
    }
}

__global__ void k_combo(const int* __restrict__ ri, const int* __restrict__ ci,
                        int* __restrict__ combo, int V) {
    int v = blockIdx.x * blockDim.x + threadIdx.x;
    if (v < V) combo[v] = ri[v] * 64 + ci[v];
}

// ---------------- weight transpose + bf16: WT[m*256 + n][k] = Wsrc_m[k][n] ----------------
// matrix order m=0..7: [q1 k1 v1 o1 q2 k2 v2 o2]
__global__ void __launch_bounds__(256) k_wt(const float* __restrict__ Wq, const float* __restrict__ Wk,
                                            const float* __restrict__ Wv, const float* __restrict__ Wo,
                                            unsigned short* __restrict__ WT) {
    __shared__ float sm[64][65];
    int blk = blockIdx.x;          // 8 matrices x 16 tiles
    int m = blk >> 4, t = blk & 15;
    int tr = t >> 2, tc = t & 3;   // k-tile, n-tile
    const float* srcs[4] = {Wq, Wk, Wv, Wo};
    const float* W = srcs[m & 3] + (size_t)(m >> 2) * 65536;
    int tid = threadIdx.x;
    for (int i = tid; i < 4096; i += 256) {
        int r = i >> 6, c = i & 63;
        sm[r][c] = W[(size_t)(tr * 64 + r) * 256 + tc * 64 + c];
    }
    __syncthreads();
    for (int i = tid; i < 4096; i += 256) {
        int n = i >> 6, k = i & 63;
        WT[(size_t)(m * 256 + tc * 64 + n) * 256 + tr * 64 + k] = (unsigned short)f2bf(sm[k][n]);
    }
}

// fused bias table matching WT row order
__global__ void __launch_bounds__(256) k_bias(const float* __restrict__ bq, const float* __restrict__ bk,
                                              const float* __restrict__ bv, const float* __restrict__ bo,
                                              float* __restrict__ biasF) {
    int m = blockIdx.x, n = threadIdx.x;
    const float* srcs[4] = {bq, bk, bv, bo};
    biasF[m * 256 + n] = srcs[m & 3][(m >> 2) * 256 + n];
}

// ---------------- PE projection tables ----------------
__global__ void __launch_bounds__(256) k_peproj(const float* __restrict__ W_in, float* __restrict__ AB) {
    __shared__ float pe[192];
    int blk = blockIdx.x;
    bool isA = blk < 256;
    int pos = isA ? blk : blk - 256;
    const float* Wb = W_in + (size_t)(isA ? 768 : 960) * 256;
    int tid = threadIdx.x;
    if (tid < 192) {
        float div = expf(-(float)(tid & ~1) * (logf(10000.0f) / 192.0f));
        float ang = (float)pos * div;
        pe[tid] = (tid & 1) ? cosf(ang) : sinf(ang);
    }
    __syncthreads();
    float acc = 0.f;
    #pragma unroll 8
    for (int d = 0; d < 192; ++d) acc = fmaf(pe[d], Wb[d * 256 + tid], acc);
    AB[blk * 256 + tid] = acc;
}

// ---------------- h0 table (bf16 out): A[r]+B[c]+b_in -> LN -> ReLU ----------------
__global__ void __launch_bounds__(256) k_h0(const float* __restrict__ AB, const float* __restrict__ b_in,
                                            const float* __restrict__ g, const float* __restrict__ b,
                                            unsigned short* __restrict__ h0t) {
    int wid = threadIdx.x >> 6, lane = threadIdx.x & 63;
    int m = blockIdx.x * 4 + wid;
    int r = m >> 6, c = m & 63;
    float4 a  = ((const float4*)(AB + (size_t)r * 256))[lane];
    float4 bb = ((const float4*)(AB + (size_t)(256 + c) * 256))[lane];
    float4 bi = ((const float4*)b_in)[lane];
    float x0 = a.x + bb.x + bi.x, x1 = a.y + bb.y + bi.y;
    float x2 = a.z + bb.z + bi.z, x3 = a.w + bb.w + bi.w;
    float s = x0 + x1 + x2 + x3;
    #pragma unroll
    for (int msk = 1; msk < 64; msk <<= 1) s += __shfl_xor(s, msk);
    float mu = s * (1.f / 256.f);
    float d0 = x0 - mu, d1 = x1 - mu, d2 = x2 - mu, d3 = x3 - mu;
    float sq = d0 * d0 + d1 * d1 + d2 * d2 + d3 * d3;
    #pragma unroll
    for (int msk = 1; msk < 64; msk <<= 1) sq += __shfl_xor(sq, msk);
    float rstd = rsqrtf(sq * (1.f / 256.f) + 1e-5f);
    float4 gv = ((const float4*)g)[lane], bv = ((const float4*)b)[lane];
    float y0 = fmaxf(fmaf(d0 * rstd, gv.x, bv.x), 0.f);
    float y1 = fmaxf(fmaf(d1 * rstd, gv.y, bv.y), 0.f);
    float y2 = fmaxf(fmaf(d2 * rstd, gv.z, bv.z), 0.f);
    float y3 = fmaxf(fmaf(d3 * rstd, gv.w, bv.w), 0.f);
    uint2 o;
    o.x = f2bf(y0) | (f2bf(y1) << 16);
    o.y = f2bf(y2) | (f2bf(y3) << 16);
    *(uint2*)(h0t + (size_t)m * 256 + lane * 4) = o;
}

// ---------------- bf16 MFMA GEMM: C[M][ldc slice] = act(A[M][256] @ W + bias) ----------------
// WT rows are output-cols (pre-transposed): WT[n][k]. BM=BN=128, BK=64, 4 waves (2x2), 64x64/wave.
template <typename TC, bool LEAKY>
__global__ void __launch_bounds__(256) k_mm(const unsigned short* __restrict__ A,
                                            const unsigned short* __restrict__ WT,
                                            const float* __restrict__ bias,
                                            TC* __restrict__ C, int M, int ldc) {
    __shared__ __align__(16) unsigned short As[128][72];
    __shared__ __align__(16) unsigned short Bs[128][72];
    int tid = threadIdx.x;
    int R0 = blockIdx.x * 128, C0 = blockIdx.y * 128;
    int lane = tid & 63, wave = tid >> 6;
    int wr = (wave >> 1) * 64, wc = (wave & 1) * 64;
    int fr = lane & 15, fq = lane >> 4;
    f32x4 acc[4][4] = {};
    for (int k0 = 0; k0 < 256; k0 += 64) {
        for (int i = tid; i < 1024; i += 256) {
            int r = i >> 3, c8 = (i & 7) * 8;
            int gr = R0 + r;
            uint4 u = make_uint4(0u, 0u, 0u, 0u);
            if (gr < M) u = *(const uint4*)(A + (size_t)gr * 256 + k0 + c8);
            *(uint4*)&As[r][c8] = u;
            *(uint4*)&Bs[r][c8] = *(const uint4*)(WT + (size_t)(C0 + r) * 256 + k0 + c8);
        }
        __syncthreads();
        #pragma unroll
        for (int ks = 0; ks < 64; ks += 32) {
            bf16x8 af[4], bfv[4];
            #pragma unroll
            for (int mi = 0; mi < 4; ++mi) af[mi] = *(const bf16x8*)&As[wr + mi * 16 + fr][ks + fq * 8];
            #pragma unroll
            for (int ni = 0; ni < 4; ++ni) bfv[ni] = *(const bf16x8*)&Bs[wc + ni * 16 + fr][ks + fq * 8];
            #pragma unroll
            for (int mi = 0; mi < 4; ++mi)
                #pragma unroll
                for (int ni = 0; ni < 4; ++ni)
                    acc[mi][ni] = __builtin_amdgcn_mfma_f32_16x16x32_bf16(af[mi], bfv[ni], acc[mi][ni], 0, 0, 0);
        }
        __syncthreads();
    }
    #pragma unroll
    for (int mi = 0; mi < 4; ++mi) {
        #pragma unroll
        for (int r = 0; r < 4; ++r) {
            int row = R0 + wr + mi * 16 + fq * 4 + r;
            if (row >= M) continue;
            #pragma unroll
            for (int ni = 0; ni < 4; ++ni) {
                int col = C0 + wc + ni * 16 + fr;
                float v = acc[mi][ni][r] + bias[col];
                if (LEAKY) v = v > 0.f ? v : SLOPE * v;
                if constexpr (std::is_same<TC, float>::value) {
                    C[(size_t)row * ldc + col] = v;
                } else {
                    C[(size_t)row * ldc + col] = (unsigned short)f2bf(v);
                }
            }
        }
    }
}

// ---------------- edge aggregation: one wave per target ----------------
// QKV rows are [Q(256) | K(256) | V(256)] bf16, row stride 768.
template <bool USE_COMBO>
__global__ void __launch_bounds__(256) k_edge(const int* __restrict__ off, const int* __restrict__ ssrc,
                                              const float* __restrict__ sew, const int* __restrict__ combo,
                                              const unsigned short* __restrict__ QKV,
                                              const float* __restrict__ We_l, const float* __restrict__ be_l,
                                              unsigned short* __restrict__ out, int V) {
    int wid = threadIdx.x >> 6, lane = threadIdx.x & 63;
    int t = blockIdx.x * 4 + wid;
    if (t >= V) return;
    int h = lane >> 4;
    int krow = USE_COMBO ? combo[t] : t;
    uint2 ku = *(const uint2*)(QKV + (size_t)krow * 768 + 256 + lane * 4);
    float k0 = bf2f(ku.x), k1 = bf2f(ku.x >> 16), k2 = bf2f(ku.y), k3 = bf2f(ku.y >> 16);
    float Weh = We_l[h], beh = be_l[h];
    float n0 = 0.f, n1 = 0.f, n2 = 0.f, n3 = 0.f, den = 0.f;
    int beg = off[t], end = off[t + 1];
    for (int e0 = beg; e0 < end; e0 += 64) {
        int nrem = end - e0; if (nrem > 64) nrem = 64;
        int sv = 0; float wv = 0.f;
        if (lane < nrem) {
            sv = ssrc[e0 + lane];
            wv = sew[e0 + lane];
            if (USE_COMBO) sv = combo[sv];
        }
        for (int i = 0; i < nrem; ++i) {
            int srow = __shfl(sv, i);
            float w = __shfl(wv, i);
            uint2 qu = *(const uint2*)(QKV + (size_t)srow * 768 + lane * 4);
            float p = bf2f(qu.x) * k0 + bf2f(qu.x >> 16) * k1 + bf2f(qu.y) * k2 + bf2f(qu.y >> 16) * k3;
            p += __shfl_xor(p, 1);
            p += __shfl_xor(p, 2);
            p += __shfl_xor(p, 4);
            p += __shfl_xor(p, 8);
            float bias = fmaf(w, Weh, beh);
            bias = bias > 0.f ? bias : SLOPE * bias;
            float ex = expf(fmaf(p, 0.125f, bias));
            den += ex;
            float cc = ex * w;
            uint2 vu = *(const uint2*)(QKV + (size_t)srow * 768 + 512 + lane * 4);
            n0 = fmaf(cc, bf2f(vu.x), n0);
            n1 = fmaf(cc, bf2f(vu.x >> 16), n1);
            n2 = fmaf(cc, bf2f(vu.y), n2);
            n3 = fmaf(cc, bf2f(vu.y >> 16), n3);
        }
    }
    float inv = 1.f / (den + 1e-16f);
    uint2 o;
    o.x = f2bf(n0 * inv) | (f2bf(n1 * inv) << 16);
    o.y = f2bf(n2 * inv) | (f2bf(n3 * inv) << 16);
    *(uint2*)(out + (size_t)t * 256 + lane * 4) = o;
}

// ---------------- launcher ----------------
extern "C" void kernel_launch(void* const* d_in, const int* in_sizes, int n_in,
                              void* d_out, int out_size, void* d_ws, size_t ws_size,
                              hipStream_t stream) {
    const int*   row_idx = (const int*)d_in[0];
    const int*   col_idx = (const int*)d_in[1];
    const int*   ei      = (const int*)d_in[2];
    const float* ew      = (const float*)d_in[3];
    const float* W_in    = (const float*)d_in[4];
    const float* b_in    = (const float*)d_in[5];
    const float* ln_g    = (const float*)d_in[6];
    const float* ln_b    = (const float*)d_in[7];
    const float* Wq      = (const float*)d_in[8];
    const float* bq      = (const float*)d_in[9];
    const float* Wk      = (const float*)d_in[10];
    const float* bk      = (const float*)d_in[11];
    const float* Wv      = (const float*)d_in[12];
    const float* bv      = (const float*)d_in[13];
    const float* Wo      = (const float*)d_in[14];
    const float* bo      = (const float*)d_in[15];
    const float* We      = (const float*)d_in[16];
    const float* be      = (const float*)d_in[17];

    const int V = in_sizes[0];
    const int E = in_sizes[3];
    const int NC = 16384;

    char* w = (char*)d_ws;
    size_t o = 0;
    auto alloc = [&](size_t bytes) -> char* {
        char* p = w + o;
        o = (o + bytes + 255) & ~(size_t)255;
        return p;
    };
    int*   cnt     = (int*)alloc((size_t)V * 4);
    int*   fill    = (int*)alloc((size_t)V * 4);
    int*   csr_off = (int*)alloc((size_t)(V + 1) * 4);
    int*   bsums   = (int*)alloc(1024 * 4);
    int*   csr_src = (int*)alloc((size_t)E * 4);
    float* csr_ew  = (float*)alloc((size_t)E * 4);
    int*   combo   = (int*)alloc((size_t)V * 4);
    float* AB      = (float*)alloc((size_t)320 * 256 * 4);
    unsigned short* WT    = (unsigned short*)alloc((size_t)2048 * 256 * 2);
    float*          biasF = (float*)alloc((size_t)2048 * 4);
    unsigned short* h0t   = (unsigned short*)alloc((size_t)NC * 256 * 2);
    unsigned short* QKV1  = (unsigned short*)alloc((size_t)NC * 768 * 2);
    unsigned short* out_e = (unsigned short*)alloc((size_t)V * 256 * 2);
    unsigned short* h1    = (unsigned short*)alloc((size_t)V * 256 * 2);
    unsigned short* QKV2  = (unsigned short*)alloc((size_t)V * 768 * 2);

    hipMemsetAsync(cnt, 0, (size_t)V * 4, stream);
    hipMemsetAsync(fill, 0, (size_t)V * 4, stream);

    int eb = (E + 255) / 256;
    int nscan = (V + 1023) / 1024;
    k_hist<<<eb, 256, 0, stream>>>(ei + E, cnt, E);
    k_scan1<<<nscan, 1024, 0, stream>>>(cnt, csr_off + 1, bsums, V);
    k_scan2<<<1, 1024, 0, stream>>>(bsums, nscan);
    k_scan3<<<nscan, 1024, 0, stream>>>(csr_off + 1, bsums, csr_off, V);
    k_scatter<<<eb, 256, 0, stream>>>(ei, ew, csr_off, fill, csr_src, csr_ew, E);
    k_combo<<<(V + 255) / 256, 256, 0, stream>>>(row_idx, col_idx, combo, V);

    k_wt<<<128, 256, 0, stream>>>(Wq, Wk, Wv, Wo, WT);
    k_bias<<<8, 256, 0, stream>>>(bq, bk, bv, bo, biasF);
    k_peproj<<<320, 256, 0, stream>>>(W_in, AB);
    k_h0<<<NC / 4, 256, 0, stream>>>(AB, b_in, ln_g, ln_b, h0t);

    // layer 1 fused QKV GEMM on the 16K combo table
    dim3 g1(NC / 128, 6);
    k_mm<unsigned short, false><<<g1, 256, 0, stream>>>(h0t, WT, biasF, QKV1, NC, 768);

    int tb = (V + 3) / 4;
    k_edge<true><<<tb, 256, 0, stream>>>(csr_off, csr_src, csr_ew, combo, QKV1, We, be, out_e, V);

    int mb = (V + 127) / 128;
    dim3 gо(mb, 2);
    dim3 gqkv(mb, 6);
    // h1 = leaky(out_e @ Wo1 + bo1)
    k_mm<unsigned short, true><<<gо, 256, 0, stream>>>(out_e, WT + (size_t)768 * 256, biasF + 768, h1, V, 256);
    // layer 2 fused QKV
    k_mm<unsigned short, false><<<gqkv, 256, 0, stream>>>(h1, WT + (size_t)1024 * 256, biasF + 1024, QKV2, V, 768);

    k_edge<false><<<tb, 256, 0, stream>>>(csr_off, csr_src, csr_ew, combo, QKV2, We + 4, be + 4, out_e, V);

    // final: d_out = leaky(out_e @ Wo2 + bo2) in f32
    k_mm<float, true><<<gо, 256, 0, stream>>>(out_e, WT + (size_t)1792 * 256, biasF + 1792, (float*)d_out, V, 256);
}